// Round 1
// baseline (219.276 us; speedup 1.0000x reference)
//
#include <hip/hip_runtime.h>

// out[b,c,i,j] = x[b,c,i,j] * (i%3!=0) * (j%3!=0)
// Derivation: the fold's scatter-add targets the exact coords the unfold read,
// so the composite is elementwise mult by separable count map; counts are 0/1
// (0 iff padded-coordinate t = idx+1 has t%3==1).

constexpr int N_TOTAL = 64 * 512 * 32 * 32;   // 33,554,432 floats
constexpr int N4      = N_TOTAL / 4;          // 8,388,608 float4

__global__ __launch_bounds__(256) void unfoldfold_mask_kernel(
    const float4* __restrict__ x, float4* __restrict__ out) {
    int idx = blockIdx.x * blockDim.x + threadIdx.x;   // grid sized exactly
    // flat float idx = idx*4; row i = (idx*4/32)%32 = (idx>>3)&31; col base j0=(idx&7)*4
    int i = (idx >> 3) & 31;
    if ((i % 3) == 0) {
        // whole row is zero: no load (row = 128B = one cache line, so no fetch)
        out[idx] = make_float4(0.f, 0.f, 0.f, 0.f);
        return;
    }
    float4 v = x[idx];
    int m = (idx & 7) << 2;  // j0 in {0,4,...,28}
    m %= 3;                  // lane l is zeroed iff (j0+l)%3==0
    if (m == 0)      { v.x = 0.f; v.w = 0.f; }
    else if (m == 1) { v.z = 0.f; }
    else             { v.y = 0.f; }
    out[idx] = v;
}

extern "C" void kernel_launch(void* const* d_in, const int* in_sizes, int n_in,
                              void* d_out, int out_size, void* d_ws, size_t ws_size,
                              hipStream_t stream) {
    const float4* x = (const float4*)d_in[0];
    float4* out = (float4*)d_out;
    unfoldfold_mask_kernel<<<N4 / 256, 256, 0, stream>>>(x, out);
}

// Round 3
// 216.178 us; speedup vs baseline: 1.0143x; 1.0143x over previous
//
#include <hip/hip_runtime.h>

// out[b,c,i,j] = x[b,c,i,j] * (i%3!=0) * (j%3!=0)
// Derivation: the fold scatter-add targets exactly the coords the unfold read,
// so the composite is an elementwise 0/1 mask, separable in i and j:
// zero iff (idx+PAD)%3==1, i.e. idx%3==0.
//
// Each thread handles 2 consecutive float4 = 32B = one half-row (row = 32
// floats = 128B). Thread t: row i = (t>>2)&31, col base j0 = (t&3)*8.
// Rows with i%3==0 are all-zero: store zeros, skip the load entirely
// (rows are 128B-aligned segments, so skipped rows cost no HBM fetch).
// Non-temporal loads/stores: zero reuse, keep L2 clean.
// NOTE: __builtin_nontemporal_* needs a true vector type, not HIP_vector_type.

typedef float vf4 __attribute__((ext_vector_type(4)));

constexpr int N_TOTAL = 64 * 512 * 32 * 32;   // 33,554,432 floats
constexpr int NT      = N_TOTAL / 8;          // 4,194,304 threads (2 float4 each)

__global__ __launch_bounds__(256) void unfoldfold_mask_kernel(
    const vf4* __restrict__ x, vf4* __restrict__ out) {
    int t = blockIdx.x * blockDim.x + threadIdx.x;   // grid sized exactly
    int i = (t >> 2) & 31;                           // row within 32x32 image
    int idx = t * 2;                                 // float4 index
    if ((i % 3) == 0) {
        vf4 z = (vf4)(0.f);
        __builtin_nontemporal_store(z, &out[idx]);
        __builtin_nontemporal_store(z, &out[idx + 1]);
        return;
    }
    vf4 a = __builtin_nontemporal_load(&x[idx]);
    vf4 b = __builtin_nontemporal_load(&x[idx + 1]);
    // j0 = (t&3)*8; j0 % 3 selects which lanes of the 8-float group are zeroed
    int m = ((t & 3) << 3) % 3;
    // lanes l in [0,8): zero iff (j0+l)%3==0
    if (m == 0)      { a.x = 0.f; a.w = 0.f; b.z = 0.f; }        // l=0,3,6
    else if (m == 1) { a.z = 0.f; b.y = 0.f; }                   // l=2,5
    else             { a.y = 0.f; b.x = 0.f; b.w = 0.f; }        // l=1,4,7
    __builtin_nontemporal_store(a, &out[idx]);
    __builtin_nontemporal_store(b, &out[idx + 1]);
}

extern "C" void kernel_launch(void* const* d_in, const int* in_sizes, int n_in,
                              void* d_out, int out_size, void* d_ws, size_t ws_size,
                              hipStream_t stream) {
    const vf4* x = (const vf4*)d_in[0];
    vf4* out = (vf4*)d_out;
    unfoldfold_mask_kernel<<<NT / 256, 256, 0, stream>>>(x, out);
}